// Round 7
// baseline (149.692 us; speedup 1.0000x reference)
//
#include <hip/hip_runtime.h>

#define NBOX 300000
#define NFEAT 85
#define NCLS 80
#define NBUCK 4096
#define CMAX 8192
#define W64 (CMAX / 64)   // 128 mask words per candidate row
#define MAXKEEP 1000
#define PRE 20            // speculative-prefetch rows per block in sweep

typedef unsigned long long u64;
typedef float f4 __attribute__((ext_vector_type(4), aligned(4)));

__device__ __forceinline__ int bucket_of(float s) {
    int b = (int)((s - 0.3f) * (4096.0f / 0.7f));
    if (b < 0) b = 0;
    if (b > NBUCK - 1) b = NBUCK - 1;
    return b;
}

__device__ __forceinline__ bool sup_iou(float by1, float bx1, float by2, float bx2, float ba,
                                        float y1, float x1, float y2, float x2, float area) {
    float iy1 = fmaxf(by1, y1), ix1 = fmaxf(bx1, x1);
    float iy2 = fminf(by2, y2), ix2 = fminf(bx2, x2);
    float inter = fmaxf(iy2 - iy1, 0.0f) * fmaxf(ix2 - ix1, 0.0f);
    float uni = ba + area - inter;
    float iou = (uni > 0.0f) ? inter / uni : 0.0f;
    return iou > 0.5f;
}

// n-th (0-based) set bit position of m; undefined if n >= popcount(m)
__device__ __forceinline__ int nth_set(u64 m, int n) {
    int pos = 0;
    int c = __popcll(m & 0xFFFFFFFFull);
    if (n >= c) { n -= c; pos = 32; m >>= 32; }
    unsigned x = (unsigned)m;
    c = __popc(x & 0xFFFFu);
    if (n >= c) { n -= c; pos += 16; x >>= 16; }
    c = __popc(x & 0xFFu);
    if (n >= c) { n -= c; pos += 8; x >>= 8; }
    c = __popc(x & 0xFu);
    if (n >= c) { n -= c; pos += 4; x >>= 4; }
    c = __popc(x & 0x3u);
    if (n >= c) { n -= c; pos += 2; x >>= 2; }
    c = x & 1u;
    if (n >= c) { pos += 1; }
    return pos;
}

__global__ void k_init(unsigned* __restrict__ hist, unsigned* __restrict__ cnt,
                       int* __restrict__ meta) {
    int i = blockIdx.x * blockDim.x + threadIdx.x;
    if (i < NBUCK) { hist[i] = 0u; cnt[i] = 0u; }
    if (i < 8) meta[i] = 0;
}

// Direct-register vectorized scores: one row/thread, 20x float4 (4B-aligned) prob
// loads. High TLP (no LDS) -> HBM-bound. conf*max(p) == max(conf*p) exactly
// (conf >= 0, RN monotone) — proven bit-exact in rounds 5/6.
__global__ void __launch_bounds__(256) k_scores(const float* __restrict__ in,
        float* __restrict__ scores, unsigned* __restrict__ hist) {
    int i = blockIdx.x * blockDim.x + threadIdx.x;
    if (i >= NBOX) return;
    const float* row = in + (size_t)i * NFEAT;
    float conf = row[4];
    const f4* p4 = (const f4*)(row + 5);   // (85*i+5)*4B: 4B-aligned
    float mx = -1.0f;
    #pragma unroll
    for (int k = 0; k < 20; ++k) {
        f4 v = p4[k];
        mx = fmaxf(mx, fmaxf(fmaxf(v.x, v.y), fmaxf(v.z, v.w)));
    }
    float best = conf * mx;
    scores[i] = best;
    if (best >= 0.3f) atomicAdd(&hist[bucket_of(best)], 1u);
}

// Suffix sums over buckets; bstar = smallest b with suffix(b) <= CMAX;
// off[b] = suffix(b+1); meta[0] = suffix(bstar) (deterministic top-prefix).
__global__ void __launch_bounds__(1024) k_thresh(const unsigned* __restrict__ hist,
                                                 unsigned* __restrict__ off,
                                                 int* __restrict__ meta) {
    __shared__ unsigned chunk[1024];
    int t = threadIdx.x;
    unsigned h[4];
    unsigned s = 0;
    #pragma unroll
    for (int j = 0; j < 4; ++j) { h[j] = hist[t * 4 + j]; s += h[j]; }
    chunk[t] = s;
    __syncthreads();
    for (int o = 1; o < 1024; o <<= 1) {
        unsigned add = (t + o < 1024) ? chunk[t + o] : 0u;
        __syncthreads();
        chunk[t] += add;
        __syncthreads();
    }
    unsigned after = (t + 1 < 1024) ? chunk[t + 1] : 0u;
    unsigned suf[5];
    suf[4] = after;
    #pragma unroll
    for (int j = 3; j >= 0; --j) suf[j] = suf[j + 1] + h[j];
    #pragma unroll
    for (int j = 0; j < 4; ++j) {
        int b = t * 4 + j;
        off[b] = suf[j] - h[j];
        unsigned sufb = suf[j];
        unsigned sufprev;
        if (b == 0) sufprev = 0xFFFFFFFFu;
        else if (j > 0) sufprev = suf[j - 1];
        else sufprev = sufb + hist[b - 1];
        if (sufb <= (unsigned)CMAX && sufprev > (unsigned)CMAX) {
            meta[1] = b;
            meta[0] = (int)sufb;
        }
    }
}

__global__ void k_scatter(const float* __restrict__ scores, const int* __restrict__ meta,
                          const unsigned* __restrict__ off, unsigned* __restrict__ cnt,
                          u64* __restrict__ unsorted) {
    int i = blockIdx.x * blockDim.x + threadIdx.x;
    if (i >= NBOX) return;
    float s = scores[i];
    if (s < 0.3f) return;
    int b = bucket_of(s);
    if (b < meta[1]) return;
    unsigned slot = off[b] + atomicAdd(&cnt[b], 1u);
    if (slot < CMAX)
        unsorted[slot] = ((u64)__float_as_uint(s) << 32) |
                         (u64)(0xFFFFFFFFu - (unsigned)i);
}

// Exact rank within bucket -> fully sorted, deterministic (keys unique).
// Also compacts each candidate's box into boxes4 (coalesced consumption downstream).
__global__ void k_rank(const float* __restrict__ in, const u64* __restrict__ unsorted,
                       const unsigned* __restrict__ off, const unsigned* __restrict__ hist,
                       const int* __restrict__ meta, u64* __restrict__ sorted,
                       float4* __restrict__ boxes4) {
    int i = blockIdx.x * blockDim.x + threadIdx.x;
    int total = meta[0];
    if (i >= total) return;
    u64 k = unsorted[i];
    float s = __uint_as_float((unsigned)(k >> 32));
    int b = bucket_of(s);
    unsigned base = off[b];
    unsigned n = hist[b];
    unsigned r = 0;
    for (unsigned u = 0; u < n; ++u) r += (unsorted[base + u] > k) ? 1u : 0u;
    sorted[base + r] = k;
    int bi = (int)(0xFFFFFFFFu - (unsigned)(k & 0xFFFFFFFFull));
    const float* p = in + (size_t)bi * NFEAT;
    boxes4[base + r] = make_float4(p[0], p[1], p[2], p[3]);  // y1,x1,y2,x2
}

// masks[i][w] bit b = (j = w*64+b) > i && IoU(i,j) > 0.5.  Words tj >= ti written
// (0 for invalid i/j). Diag blocks also emit validmask[ti] (bit r = row has
// positive extents; zero-extent rows provably have all-zero mask rows).
__global__ void __launch_bounds__(256) k_masks(const float4* __restrict__ boxes4,
        const int* __restrict__ meta, u64* __restrict__ masks,
        u64* __restrict__ validmask) {
    int ti = blockIdx.y, tj = blockIdx.x;
    if (tj < ti) return;
    int count = meta[0];
    if (count > CMAX) count = CMAX;
    __shared__ float4 rb[64];
    int t = threadIdx.x;
    if (t < 64) {
        int r = ti * 64 + t;
        rb[t] = (r < count) ? boxes4[r] : make_float4(0.f, 0.f, 0.f, 0.f);
    }
    int lane = t & 63, wid = t >> 6;
    int cj = tj * 64 + lane;
    bool cvalid = (cj < count);
    float4 cb = cvalid ? boxes4[cj] : make_float4(0.f, 0.f, 0.f, 0.f);
    float carea = (cb.z - cb.x) * (cb.w - cb.y);
    __syncthreads();
    if (ti == tj && t < 64) {   // wave 0 exactly: ballot is wave-wide
        float4 b = rb[t];
        bool v = (b.z > b.x) && (b.w > b.y);
        u64 vb = __ballot(v ? 1 : 0);
        if (t == 0) validmask[ti] = vb;
    }
    #pragma unroll
    for (int r = 0; r < 16; ++r) {
        int i = ti * 64 + wid * 16 + r;
        float4 b = rb[wid * 16 + r];
        float ba = (b.z - b.x) * (b.w - b.y);
        bool s = cvalid && (cj > i) && (i < count) &&
                 sup_iou(b.x, b.y, b.z, b.w, ba, cb.x, cb.y, cb.z, cb.w, carea);
        u64 word = __ballot(s ? 1 : 0);
        if (lane == 0) masks[(size_t)i * W64 + tj] = word;
    }
}

// Greedy sweep, one wave. Lane l owns R/valid words 2l, 2l+1.
// Per block w: BEFORE the greedy chain, issue speculative DMA prefetch of block
// w+1's candidate rows (spec = ~R&valid with R lagging one block = provable
// superset of next block's kept&valid; masked by actual kept at use) into an
// LDS double-buffer via global_load_lds (HW scatters lane l's 16B to off 16l),
// plus the diag word. Rows land during this block's chain -> counted
// vmcnt(21) wait is ~free. Invalid (degenerate) rows are all-zero, never loaded.
__global__ void __launch_bounds__(64) k_sweep(const u64* __restrict__ masks,
        const u64* __restrict__ validmask, int* __restrict__ meta,
        int* __restrict__ keptpos) {
    __shared__ __align__(16) u64 stage[2][PRE][W64];  // 40 KB
    int lane = threadIdx.x;
    int count = meta[0];
    if (count > CMAX) count = CMAX;
    int nblk = (count + 63) >> 6;
    u64 r0 = 0ull, r1 = 0ull;
    u64 v0 = validmask[2 * lane], v1 = validmask[2 * lane + 1];
    int nk = 0;
    u64 spec_use = 0ull, diag_cur = 0ull;

    if (nblk > 0) {  // prologue: exact spec for block 0 (R=0), buf 0
        u64 vm0 = (count >= 64) ? ~0ull : ((1ull << count) - 1ull);
        spec_use = __shfl(v0, 0) & vm0;
        u64 t = spec_use;
        #pragma unroll
        for (int k = 0; k < PRE; ++k) {
            bool has = (t != 0ull);
            int b = has ? (__ffsll(t) - 1) : 0;   // dummy row 0 when absent
            t &= t - 1;
            __builtin_amdgcn_global_load_lds(
                (const __attribute__((address_space(1))) void*)(masks + (size_t)b * W64 + 2 * lane),
                (__attribute__((address_space(3))) void*)&stage[0][k][0], 16, 0, 0);
        }
        diag_cur = masks[(size_t)lane * W64];
    }

    for (int w = 0; w < nblk; ++w) {
        int buf = w & 1;
        int base = w << 6;
        int rc = count - base;
        u64 vm = (rc >= 64) ? ~0ull : ((1ull << rc) - 1ull);
        u64 rw = __shfl((w & 1) ? r1 : r0, w >> 1);
        u64 surv = ~rw & vm;

        bool more = (w + 1 < nblk);
        u64 spec_next = 0ull, diag_next = 0ull;
        if (more) {  // speculative issue for w+1 (R lags one block: superset-safe)
            int b2 = base + 64, w2 = w + 1;
            int rc2 = count - b2;
            u64 vm2 = (rc2 >= 64) ? ~0ull : ((1ull << rc2) - 1ull);
            u64 rw2 = __shfl((w2 & 1) ? r1 : r0, w2 >> 1);
            u64 vw2 = __shfl((w2 & 1) ? v1 : v0, w2 >> 1);
            spec_next = ~rw2 & vw2 & vm2;
            u64 t = spec_next;
            #pragma unroll
            for (int k = 0; k < PRE; ++k) {
                bool has = (t != 0ull);
                int b = has ? (__ffsll(t) - 1) : 0;
                t &= t - 1;
                __builtin_amdgcn_global_load_lds(
                    (const __attribute__((address_space(1))) void*)(masks + (size_t)(b2 + b) * W64 + 2 * lane),
                    (__attribute__((address_space(3))) void*)&stage[buf ^ 1][k][0], 16, 0, 0);
            }
            diag_next = masks[(size_t)(b2 + lane) * W64 + w2];
        }

        // in-block greedy: only nonzero-diag candidates enter the serial chain
        u64 Z = __ballot(diag_cur == 0ull);
        u64 rem_l = 0ull;
        u64 mnz = surv & ~Z;
        while (mnz) {
            int b = __ffsll(mnz) - 1;
            mnz &= mnz - 1;
            if ((rem_l >> b) & 1ull) continue;
            u64 db = __shfl(diag_cur, b);
            rem_l |= db;
            mnz &= ~db;
        }
        u64 kept = surv & ~rem_l;

        // truncate to exactly MAXKEEP in index order
        int kp = __popcll(kept);
        int room = MAXKEEP - nk;
        if (kp > room) {
            while (kp > room) { kept &= ~(1ull << (63 - __clzll(kept))); --kp; }
        }
        bool full = (nk + kp >= MAXKEEP);

        if (!full) {
            // wait for rows(w): exactly 21 guaranteed-newer VMEM ops (20 DMA + diag)
            if (more) asm volatile("s_waitcnt vmcnt(21)" ::: "memory");
            else      asm volatile("s_waitcnt vmcnt(0)"  ::: "memory");
            __builtin_amdgcn_sched_barrier(0);
            u64 t = spec_use;
            u64 alo = 0ull, ahi = 0ull;
            #pragma unroll
            for (int k = 0; k < PRE; ++k) {
                bool has = (t != 0ull);
                int b = has ? (__ffsll(t) - 1) : 0;
                t &= t - 1;
                bool use = has && (((kept >> b) & 1ull) != 0ull);
                u64 lo = stage[buf][k][2 * lane];
                u64 hi = stage[buf][k][2 * lane + 1];
                alo |= use ? lo : 0ull;
                ahi |= use ? hi : 0ull;
            }
            u64 km = kept & t;  // kept&valid rows beyond PRE cap (rare)
            while (km) {
                int b = __ffsll(km) - 1;
                km &= km - 1;
                const u64* p = masks + (size_t)(base + b) * W64 + 2 * lane;
                alo |= p[0]; ahi |= p[1];
            }
            r0 |= alo; r1 |= ahi;
        }

        if (lane < kp) keptpos[nk + lane] = base + nth_set(kept, lane);
        nk += kp;
        if (full) break;
        spec_use = spec_next;
        diag_cur = diag_next;
    }
    if (lane == 0) meta[2] = nk;
}

// One wave per output row: lanes cover the 80 classes, butterfly argmax with
// strict-greater / lower-index tiebreak (== jnp.argmax first occurrence).
__global__ void __launch_bounds__(256) k_output(const float* __restrict__ in,
        const u64* __restrict__ gkeys, const int* __restrict__ meta,
        const int* __restrict__ keptpos, float* __restrict__ out) {
    int gw = (blockIdx.x * blockDim.x + threadIdx.x) >> 6;  // row
    int lane = threadIdx.x & 63;
    if (gw >= MAXKEEP) return;
    int kc = meta[2];
    if (gw < kc) {
        int pos = keptpos[gw];
        u64 key = gkeys[pos];
        int bi = (int)(0xFFFFFFFFu - (unsigned)(key & 0xFFFFFFFFull));
        const float* row = in + (size_t)bi * NFEAT;
        float conf = row[4];
        float v0 = (lane < NCLS) ? conf * row[5 + lane] : -1.0f;
        float v1 = (lane < NCLS - 64) ? conf * row[5 + 64 + lane] : -1.0f;
        float bv = (v1 > v0) ? v1 : v0;          // tie -> v0 (smaller idx)
        int bix = (v1 > v0) ? (64 + lane) : lane;
        #pragma unroll
        for (int o = 1; o < 64; o <<= 1) {
            float ov = __shfl_xor(bv, o);
            int oi = __shfl_xor(bix, o);
            if (ov > bv || (ov == bv && oi < bix)) { bv = ov; bix = oi; }
        }
        float wv = 0.f;
        if (lane < 4) wv = row[lane];
        else if (lane == 4) wv = (float)bix;
        else wv = bv;
        if (lane < 6) out[gw * 6 + lane] = wv;
    } else {
        if (lane < 6) out[gw * 6 + lane] = 0.f;
    }
}

extern "C" void kernel_launch(void* const* d_in, const int* in_sizes, int n_in,
                              void* d_out, int out_size, void* d_ws, size_t ws_size,
                              hipStream_t stream) {
    const float* in = (const float*)d_in[0];
    float* out = (float*)d_out;
    char* ws = (char*)d_ws;
    // ws layout (bytes). masks OVERLAYS sort-phase scratch (dead before k_masks).
    //   [0, 65536)              sorted    u64[8192]
    //   [65536, 65600)          meta      i32[8]  {0:total, 1:bstar, 2:kept count}
    //   [65600, 69696)          keptpos   i32[1024]
    //   [69696, 70720)          validmask u64[128]
    //   [70720, 201792)         boxes4    float4[8192]
    //   [201792, 8590400)       masks     u64[8192*128]  (8 MB), overlaying:
    //     [201792, 1401792)       scores   f32[300000]
    //     [1401792, 1418176)      hist     u32[4096]
    //     [1418176, 1434560)      cnt      u32[4096]
    //     [1434560, 1450944)      off      u32[4096]
    //     [1450944, 1516480)      unsorted u64[8192]
    u64* sorted = (u64*)(ws);
    int* meta = (int*)(ws + 65536);
    int* keptpos = (int*)(ws + 65600);
    u64* validmask = (u64*)(ws + 69696);
    float4* boxes4 = (float4*)(ws + 70720);
    u64* masks = (u64*)(ws + 201792);
    float* scores = (float*)(ws + 201792);
    unsigned* hist = (unsigned*)(ws + 1401792);
    unsigned* cnt = (unsigned*)(ws + 1418176);
    unsigned* off = (unsigned*)(ws + 1434560);
    u64* unsorted = (u64*)(ws + 1450944);

    k_init<<<dim3(16), dim3(256), 0, stream>>>(hist, cnt, meta);
    k_scores<<<dim3((NBOX + 255) / 256), dim3(256), 0, stream>>>(in, scores, hist);
    k_thresh<<<dim3(1), dim3(1024), 0, stream>>>(hist, off, meta);
    k_scatter<<<dim3((NBOX + 255) / 256), dim3(256), 0, stream>>>(scores, meta, off, cnt, unsorted);
    k_rank<<<dim3(CMAX / 256), dim3(256), 0, stream>>>(in, unsorted, off, hist, meta, sorted, boxes4);
    k_masks<<<dim3(W64, W64), dim3(256), 0, stream>>>(boxes4, meta, masks, validmask);
    k_sweep<<<dim3(1), dim3(64), 0, stream>>>(masks, validmask, meta, keptpos);
    k_output<<<dim3((MAXKEEP * 64 + 255) / 256), dim3(256), 0, stream>>>(in, sorted, meta, keptpos, out);
}

// Round 8
// 148.473 us; speedup vs baseline: 1.0082x; 1.0082x over previous
//
#include <hip/hip_runtime.h>

#define NBOX 300000
#define NFEAT 85
#define NCLS 80
#define NBUCK 4096
#define CMAX 8192
#define W64 (CMAX / 64)   // 128 mask words per candidate row
#define MAXKEEP 1000
#define PRE 20            // speculative-prefetch rows per block in sweep
#define SC_ROWS 64        // k_scores tile rows (21760 B LDS -> 7 blocks/CU)

typedef unsigned long long u64;
typedef float f4a __attribute__((ext_vector_type(4), aligned(16)));

__device__ __forceinline__ int bucket_of(float s) {
    int b = (int)((s - 0.3f) * (4096.0f / 0.7f));
    if (b < 0) b = 0;
    if (b > NBUCK - 1) b = NBUCK - 1;
    return b;
}

__device__ __forceinline__ bool sup_iou(float by1, float bx1, float by2, float bx2, float ba,
                                        float y1, float x1, float y2, float x2, float area) {
    float iy1 = fmaxf(by1, y1), ix1 = fmaxf(bx1, x1);
    float iy2 = fminf(by2, y2), ix2 = fminf(bx2, x2);
    float inter = fmaxf(iy2 - iy1, 0.0f) * fmaxf(ix2 - ix1, 0.0f);
    float uni = ba + area - inter;
    float iou = (uni > 0.0f) ? inter / uni : 0.0f;
    return iou > 0.5f;
}

// n-th (0-based) set bit position of m; undefined if n >= popcount(m)
__device__ __forceinline__ int nth_set(u64 m, int n) {
    int pos = 0;
    int c = __popcll(m & 0xFFFFFFFFull);
    if (n >= c) { n -= c; pos = 32; m >>= 32; }
    unsigned x = (unsigned)m;
    c = __popc(x & 0xFFFFu);
    if (n >= c) { n -= c; pos += 16; x >>= 16; }
    c = __popc(x & 0xFFu);
    if (n >= c) { n -= c; pos += 8; x >>= 8; }
    c = __popc(x & 0xFu);
    if (n >= c) { n -= c; pos += 4; x >>= 4; }
    c = __popc(x & 0x3u);
    if (n >= c) { n -= c; pos += 2; x >>= 2; }
    c = x & 1u;
    if (n >= c) { pos += 1; }
    return pos;
}

__global__ void k_init(unsigned* __restrict__ hist, unsigned* __restrict__ cnt,
                       int* __restrict__ meta) {
    int i = blockIdx.x * blockDim.x + threadIdx.x;
    if (i < NBUCK) { hist[i] = 0u; cnt[i] = 0u; }
    if (i < 8) meta[i] = 0;
}

// Coalesced staged scores with real occupancy: 256 thr / 64-row tile / 21.76 KB
// LDS (7 blocks/CU, 28 waves/CU -> cross-block TLP hides HBM latency).
// Stage: flat float4 copy (fully coalesced). Compute: quarter-row per thread
// (20 classes), 4-lane shfl_xor max combine (fmax order-invariant, exact),
// then conf*max == max(conf*p) exactly (conf >= 0, RN monotone; proven R5-R7).
__global__ void __launch_bounds__(256) k_scores(const float* __restrict__ in,
        float* __restrict__ scores, unsigned* __restrict__ hist) {
    __shared__ float lds[SC_ROWS * NFEAT];  // 21760 B
    int t = threadIdx.x;
    long long rbase = (long long)blockIdx.x * SC_ROWS;
    int rows = (NBOX - rbase < SC_ROWS) ? (int)(NBOX - rbase) : SC_ROWS;
    int nfl = rows * NFEAT;
    int nf4 = nfl >> 2;               // rows*85 % 4 == 0 for rows in {64, 32}
    const f4a* src = (const f4a*)(in + rbase * NFEAT);  // 21760*b bytes: 16B-aligned
    f4a* dst = (f4a*)lds;
    for (int k = t; k < nf4; k += 256) dst[k] = src[k];
    for (int k = (nf4 << 2) + t; k < nfl; k += 256) lds[k] = in[rbase * NFEAT + k];
    __syncthreads();
    int row = t >> 2, part = t & 3;
    if (row < rows) {
        const float* r = lds + row * NFEAT;
        const float* p = r + 5 + 20 * part;
        float mx = p[0];
        #pragma unroll
        for (int j = 1; j < 20; ++j) mx = fmaxf(mx, p[j]);
        mx = fmaxf(mx, __shfl_xor(mx, 1));
        mx = fmaxf(mx, __shfl_xor(mx, 2));
        if (part == 0) {
            float best = r[4] * mx;
            scores[rbase + row] = best;
            if (best >= 0.3f) atomicAdd(&hist[bucket_of(best)], 1u);
        }
    }
}

// Suffix sums over buckets; bstar = smallest b with suffix(b) <= CMAX;
// off[b] = suffix(b+1); meta[0] = suffix(bstar) (deterministic top-prefix).
__global__ void __launch_bounds__(1024) k_thresh(const unsigned* __restrict__ hist,
                                                 unsigned* __restrict__ off,
                                                 int* __restrict__ meta) {
    __shared__ unsigned chunk[1024];
    int t = threadIdx.x;
    unsigned h[4];
    unsigned s = 0;
    #pragma unroll
    for (int j = 0; j < 4; ++j) { h[j] = hist[t * 4 + j]; s += h[j]; }
    chunk[t] = s;
    __syncthreads();
    for (int o = 1; o < 1024; o <<= 1) {
        unsigned add = (t + o < 1024) ? chunk[t + o] : 0u;
        __syncthreads();
        chunk[t] += add;
        __syncthreads();
    }
    unsigned after = (t + 1 < 1024) ? chunk[t + 1] : 0u;
    unsigned suf[5];
    suf[4] = after;
    #pragma unroll
    for (int j = 3; j >= 0; --j) suf[j] = suf[j + 1] + h[j];
    #pragma unroll
    for (int j = 0; j < 4; ++j) {
        int b = t * 4 + j;
        off[b] = suf[j] - h[j];
        unsigned sufb = suf[j];
        unsigned sufprev;
        if (b == 0) sufprev = 0xFFFFFFFFu;
        else if (j > 0) sufprev = suf[j - 1];
        else sufprev = sufb + hist[b - 1];
        if (sufb <= (unsigned)CMAX && sufprev > (unsigned)CMAX) {
            meta[1] = b;
            meta[0] = (int)sufb;
        }
    }
}

__global__ void k_scatter(const float* __restrict__ scores, const int* __restrict__ meta,
                          const unsigned* __restrict__ off, unsigned* __restrict__ cnt,
                          u64* __restrict__ unsorted) {
    int i = blockIdx.x * blockDim.x + threadIdx.x;
    if (i >= NBOX) return;
    float s = scores[i];
    if (s < 0.3f) return;
    int b = bucket_of(s);
    if (b < meta[1]) return;
    unsigned slot = off[b] + atomicAdd(&cnt[b], 1u);
    if (slot < CMAX)
        unsorted[slot] = ((u64)__float_as_uint(s) << 32) |
                         (u64)(0xFFFFFFFFu - (unsigned)i);
}

// Exact rank within bucket -> fully sorted, deterministic (keys unique).
// Also compacts each candidate's box into boxes4 (coalesced consumption downstream).
__global__ void k_rank(const float* __restrict__ in, const u64* __restrict__ unsorted,
                       const unsigned* __restrict__ off, const unsigned* __restrict__ hist,
                       const int* __restrict__ meta, u64* __restrict__ sorted,
                       float4* __restrict__ boxes4) {
    int i = blockIdx.x * blockDim.x + threadIdx.x;
    int total = meta[0];
    if (i >= total) return;
    u64 k = unsorted[i];
    float s = __uint_as_float((unsigned)(k >> 32));
    int b = bucket_of(s);
    unsigned base = off[b];
    unsigned n = hist[b];
    unsigned r = 0;
    for (unsigned u = 0; u < n; ++u) r += (unsorted[base + u] > k) ? 1u : 0u;
    sorted[base + r] = k;
    int bi = (int)(0xFFFFFFFFu - (unsigned)(k & 0xFFFFFFFFull));
    const float* p = in + (size_t)bi * NFEAT;
    boxes4[base + r] = make_float4(p[0], p[1], p[2], p[3]);  // y1,x1,y2,x2
}

// masks[i][w] bit b = (j = w*64+b) > i && IoU(i,j) > 0.5.  Words tj >= ti written
// (0 for invalid i/j). Diag blocks also emit validmask[ti] (bit r = row has
// positive extents; zero-extent rows provably have all-zero mask rows).
__global__ void __launch_bounds__(256) k_masks(const float4* __restrict__ boxes4,
        const int* __restrict__ meta, u64* __restrict__ masks,
        u64* __restrict__ validmask) {
    int ti = blockIdx.y, tj = blockIdx.x;
    if (tj < ti) return;
    int count = meta[0];
    if (count > CMAX) count = CMAX;
    __shared__ float4 rb[64];
    int t = threadIdx.x;
    if (t < 64) {
        int r = ti * 64 + t;
        rb[t] = (r < count) ? boxes4[r] : make_float4(0.f, 0.f, 0.f, 0.f);
    }
    int lane = t & 63, wid = t >> 6;
    int cj = tj * 64 + lane;
    bool cvalid = (cj < count);
    float4 cb = cvalid ? boxes4[cj] : make_float4(0.f, 0.f, 0.f, 0.f);
    float carea = (cb.z - cb.x) * (cb.w - cb.y);
    __syncthreads();
    if (ti == tj && t < 64) {   // wave 0 exactly: ballot is wave-wide
        float4 b = rb[t];
        bool v = (b.z > b.x) && (b.w > b.y);
        u64 vb = __ballot(v ? 1 : 0);
        if (t == 0) validmask[ti] = vb;
    }
    #pragma unroll
    for (int r = 0; r < 16; ++r) {
        int i = ti * 64 + wid * 16 + r;
        float4 b = rb[wid * 16 + r];
        float ba = (b.z - b.x) * (b.w - b.y);
        bool s = cvalid && (cj > i) && (i < count) &&
                 sup_iou(b.x, b.y, b.z, b.w, ba, cb.x, cb.y, cb.z, cb.w, carea);
        u64 word = __ballot(s ? 1 : 0);
        if (lane == 0) masks[(size_t)i * W64 + tj] = word;
    }
}

// Greedy sweep, one wave. Lane l owns R/valid words 2l, 2l+1.
// Per block w: BEFORE the greedy chain, issue speculative DMA prefetch of block
// w+1's candidate rows (spec = ~R&valid with R lagging one block = provable
// superset of next block's kept&valid; masked by actual kept at use) into an
// LDS double-buffer via global_load_lds, plus the diag word. Rows land during
// this block's chain -> counted vmcnt(21) wait is ~free. Invalid (degenerate)
// rows are all-zero, never loaded.
__global__ void __launch_bounds__(64) k_sweep(const u64* __restrict__ masks,
        const u64* __restrict__ validmask, int* __restrict__ meta,
        int* __restrict__ keptpos) {
    __shared__ __align__(16) u64 stage[2][PRE][W64];  // 40 KB
    int lane = threadIdx.x;
    int count = meta[0];
    if (count > CMAX) count = CMAX;
    int nblk = (count + 63) >> 6;
    u64 r0 = 0ull, r1 = 0ull;
    u64 v0 = validmask[2 * lane], v1 = validmask[2 * lane + 1];
    int nk = 0;
    u64 spec_use = 0ull, diag_cur = 0ull;

    if (nblk > 0) {  // prologue: exact spec for block 0 (R=0), buf 0
        u64 vm0 = (count >= 64) ? ~0ull : ((1ull << count) - 1ull);
        spec_use = __shfl(v0, 0) & vm0;
        u64 t = spec_use;
        #pragma unroll
        for (int k = 0; k < PRE; ++k) {
            bool has = (t != 0ull);
            int b = has ? (__ffsll(t) - 1) : 0;   // dummy row 0 when absent
            t &= t - 1;
            __builtin_amdgcn_global_load_lds(
                (const __attribute__((address_space(1))) void*)(masks + (size_t)b * W64 + 2 * lane),
                (__attribute__((address_space(3))) void*)&stage[0][k][0], 16, 0, 0);
        }
        diag_cur = masks[(size_t)lane * W64];
    }

    for (int w = 0; w < nblk; ++w) {
        int buf = w & 1;
        int base = w << 6;
        int rc = count - base;
        u64 vm = (rc >= 64) ? ~0ull : ((1ull << rc) - 1ull);
        u64 rw = __shfl((w & 1) ? r1 : r0, w >> 1);
        u64 surv = ~rw & vm;

        bool more = (w + 1 < nblk);
        u64 spec_next = 0ull, diag_next = 0ull;
        if (more) {  // speculative issue for w+1 (R lags one block: superset-safe)
            int b2 = base + 64, w2 = w + 1;
            int rc2 = count - b2;
            u64 vm2 = (rc2 >= 64) ? ~0ull : ((1ull << rc2) - 1ull);
            u64 rw2 = __shfl((w2 & 1) ? r1 : r0, w2 >> 1);
            u64 vw2 = __shfl((w2 & 1) ? v1 : v0, w2 >> 1);
            spec_next = ~rw2 & vw2 & vm2;
            u64 t = spec_next;
            #pragma unroll
            for (int k = 0; k < PRE; ++k) {
                bool has = (t != 0ull);
                int b = has ? (__ffsll(t) - 1) : 0;
                t &= t - 1;
                __builtin_amdgcn_global_load_lds(
                    (const __attribute__((address_space(1))) void*)(masks + (size_t)(b2 + b) * W64 + 2 * lane),
                    (__attribute__((address_space(3))) void*)&stage[buf ^ 1][k][0], 16, 0, 0);
            }
            diag_next = masks[(size_t)(b2 + lane) * W64 + w2];
        }

        // in-block greedy: only nonzero-diag candidates enter the serial chain
        u64 Z = __ballot(diag_cur == 0ull);
        u64 rem_l = 0ull;
        u64 mnz = surv & ~Z;
        while (mnz) {
            int b = __ffsll(mnz) - 1;
            mnz &= mnz - 1;
            if ((rem_l >> b) & 1ull) continue;
            u64 db = __shfl(diag_cur, b);
            rem_l |= db;
            mnz &= ~db;
        }
        u64 kept = surv & ~rem_l;

        // truncate to exactly MAXKEEP in index order
        int kp = __popcll(kept);
        int room = MAXKEEP - nk;
        if (kp > room) {
            while (kp > room) { kept &= ~(1ull << (63 - __clzll(kept))); --kp; }
        }
        bool full = (nk + kp >= MAXKEEP);

        if (!full) {
            // wait for rows(w): exactly 21 guaranteed-newer VMEM ops (20 DMA + diag)
            if (more) asm volatile("s_waitcnt vmcnt(21)" ::: "memory");
            else      asm volatile("s_waitcnt vmcnt(0)"  ::: "memory");
            __builtin_amdgcn_sched_barrier(0);
            u64 t = spec_use;
            u64 alo = 0ull, ahi = 0ull;
            #pragma unroll
            for (int k = 0; k < PRE; ++k) {
                bool has = (t != 0ull);
                int b = has ? (__ffsll(t) - 1) : 0;
                t &= t - 1;
                bool use = has && (((kept >> b) & 1ull) != 0ull);
                u64 lo = stage[buf][k][2 * lane];
                u64 hi = stage[buf][k][2 * lane + 1];
                alo |= use ? lo : 0ull;
                ahi |= use ? hi : 0ull;
            }
            u64 km = kept & t;  // kept&valid rows beyond PRE cap (rare)
            while (km) {
                int b = __ffsll(km) - 1;
                km &= km - 1;
                const u64* p = masks + (size_t)(base + b) * W64 + 2 * lane;
                alo |= p[0]; ahi |= p[1];
            }
            r0 |= alo; r1 |= ahi;
        }

        if (lane < kp) keptpos[nk + lane] = base + nth_set(kept, lane);
        nk += kp;
        if (full) break;
        spec_use = spec_next;
        diag_cur = diag_next;
    }
    if (lane == 0) meta[2] = nk;
}

// One wave per output row: lanes cover the 80 classes, butterfly argmax with
// strict-greater / lower-index tiebreak (== jnp.argmax first occurrence).
__global__ void __launch_bounds__(256) k_output(const float* __restrict__ in,
        const u64* __restrict__ gkeys, const int* __restrict__ meta,
        const int* __restrict__ keptpos, float* __restrict__ out) {
    int gw = (blockIdx.x * blockDim.x + threadIdx.x) >> 6;  // row
    int lane = threadIdx.x & 63;
    if (gw >= MAXKEEP) return;
    int kc = meta[2];
    if (gw < kc) {
        int pos = keptpos[gw];
        u64 key = gkeys[pos];
        int bi = (int)(0xFFFFFFFFu - (unsigned)(key & 0xFFFFFFFFull));
        const float* row = in + (size_t)bi * NFEAT;
        float conf = row[4];
        float v0 = (lane < NCLS) ? conf * row[5 + lane] : -1.0f;
        float v1 = (lane < NCLS - 64) ? conf * row[5 + 64 + lane] : -1.0f;
        float bv = (v1 > v0) ? v1 : v0;          // tie -> v0 (smaller idx)
        int bix = (v1 > v0) ? (64 + lane) : lane;
        #pragma unroll
        for (int o = 1; o < 64; o <<= 1) {
            float ov = __shfl_xor(bv, o);
            int oi = __shfl_xor(bix, o);
            if (ov > bv || (ov == bv && oi < bix)) { bv = ov; bix = oi; }
        }
        float wv = 0.f;
        if (lane < 4) wv = row[lane];
        else if (lane == 4) wv = (float)bix;
        else wv = bv;
        if (lane < 6) out[gw * 6 + lane] = wv;
    } else {
        if (lane < 6) out[gw * 6 + lane] = 0.f;
    }
}

extern "C" void kernel_launch(void* const* d_in, const int* in_sizes, int n_in,
                              void* d_out, int out_size, void* d_ws, size_t ws_size,
                              hipStream_t stream) {
    const float* in = (const float*)d_in[0];
    float* out = (float*)d_out;
    char* ws = (char*)d_ws;
    // ws layout (bytes). masks OVERLAYS sort-phase scratch (dead before k_masks).
    //   [0, 65536)              sorted    u64[8192]
    //   [65536, 65600)          meta      i32[8]  {0:total, 1:bstar, 2:kept count}
    //   [65600, 69696)          keptpos   i32[1024]
    //   [69696, 70720)          validmask u64[128]
    //   [70720, 201792)         boxes4    float4[8192]
    //   [201792, 8590400)       masks     u64[8192*128]  (8 MB), overlaying:
    //     [201792, 1401792)       scores   f32[300000]
    //     [1401792, 1418176)      hist     u32[4096]
    //     [1418176, 1434560)      cnt      u32[4096]
    //     [1434560, 1450944)      off      u32[4096]
    //     [1450944, 1516480)      unsorted u64[8192]
    u64* sorted = (u64*)(ws);
    int* meta = (int*)(ws + 65536);
    int* keptpos = (int*)(ws + 65600);
    u64* validmask = (u64*)(ws + 69696);
    float4* boxes4 = (float4*)(ws + 70720);
    u64* masks = (u64*)(ws + 201792);
    float* scores = (float*)(ws + 201792);
    unsigned* hist = (unsigned*)(ws + 1401792);
    unsigned* cnt = (unsigned*)(ws + 1418176);
    unsigned* off = (unsigned*)(ws + 1434560);
    u64* unsorted = (u64*)(ws + 1450944);

    k_init<<<dim3(16), dim3(256), 0, stream>>>(hist, cnt, meta);
    k_scores<<<dim3((NBOX + SC_ROWS - 1) / SC_ROWS), dim3(256), 0, stream>>>(in, scores, hist);
    k_thresh<<<dim3(1), dim3(1024), 0, stream>>>(hist, off, meta);
    k_scatter<<<dim3((NBOX + 255) / 256), dim3(256), 0, stream>>>(scores, meta, off, cnt, unsorted);
    k_rank<<<dim3(CMAX / 256), dim3(256), 0, stream>>>(in, unsorted, off, hist, meta, sorted, boxes4);
    k_masks<<<dim3(W64, W64), dim3(256), 0, stream>>>(boxes4, meta, masks, validmask);
    k_sweep<<<dim3(1), dim3(64), 0, stream>>>(masks, validmask, meta, keptpos);
    k_output<<<dim3((MAXKEEP * 64 + 255) / 256), dim3(256), 0, stream>>>(in, sorted, meta, keptpos, out);
}